// Round 1
// baseline (104.858 us; speedup 1.0000x reference)
//
#include <hip/hip_runtime.h>

typedef float f32x4 __attribute__((ext_vector_type(4)));
typedef __bf16 bf16x8 __attribute__((ext_vector_type(8)));

constexpr int V = 4096;

__device__ __forceinline__ unsigned short f2bf(float f) {
    unsigned int u = __float_as_uint(f);
    u += 0x7FFFu + ((u >> 16) & 1u);           // round-to-nearest-even
    return (unsigned short)(u >> 16);
}

// ---- kernel 1: z = W @ xv + b  -> bf16 (384 x 4096) --------------------
__global__ __launch_bounds__(256) void k_z(const float* __restrict__ x,
                                           const float* __restrict__ W,
                                           const float* __restrict__ b,
                                           unsigned short* __restrict__ zb) {
    __shared__ float Ws[8 * 128];
    __shared__ float bs[8];
    const int rg = blockIdx.x;   // 48 groups of 8 output rows
    const int vb = blockIdx.y;   // 16 v-blocks of 256
    const int t  = threadIdx.x;
    reinterpret_cast<f32x4*>(Ws)[t] = reinterpret_cast<const f32x4*>(W + rg * 1024)[t];
    if (t < 8) bs[t] = b[rg * 8 + t];
    __syncthreads();
    const int v = vb * 256 + t;
    float acc[8] = {};
    for (int j = 0; j < 128; ++j) {
        const float xj = x[j * V + v];
        #pragma unroll
        for (int q = 0; q < 8; ++q) acc[q] = fmaf(Ws[q * 128 + j], xj, acc[q]);
    }
    #pragma unroll
    for (int q = 0; q < 8; ++q)
        zb[(size_t)(rg * 8 + q) * V + v] = f2bf(acc[q] + bs[q]);
}

// ---- kernel 2: partial[p,kh] = z[p] @ A[p][k-half]  (bf16 MFMA) --------
// grid (128 n-tiles, 3 p, 2 k-halves), 256 threads = 4 waves.
// Block tile: 128 M x 32 N, K-slab 2048, BK=64.
__global__ __launch_bounds__(256) void k_gemm(const unsigned short* __restrict__ zb,
                                              const float* __restrict__ A,
                                              float* __restrict__ partial) {
    __shared__ unsigned short Bt[32][72];   // [n][k] bf16, pitch 72 (144B, 16B aligned)
    const int nt = blockIdx.x;        // 0..127
    const int p  = blockIdx.y;        // 0..2
    const int kh = blockIdx.z;        // 0..1
    const int n0 = nt * 32;
    const int kbase = kh * 2048;
    const int t    = threadIdx.x;
    const int wid  = t >> 6;
    const int lane = t & 63;
    const int lrow = lane & 15;
    const int g    = lane >> 4;

    const float* Ap = A + (size_t)p * V * V;
    const unsigned short* Zw = zb + ((size_t)p * 128 + wid * 32) * V;

    const int kk = t >> 2;      // staging row 0..63
    const int c4 = t & 3;       // staging col-quad

    f32x4 acc00 = {}, acc01 = {}, acc10 = {}, acc11 = {};

    for (int k0 = kbase; k0 < kbase + 2048; k0 += 64) {
        const float* src = Ap + (size_t)(k0 + kk) * V + n0 + c4 * 4;
        f32x4 av0 = *reinterpret_cast<const f32x4*>(src);
        f32x4 av1 = *reinterpret_cast<const f32x4*>(src + 16);
        __syncthreads();                       // previous iter's reads done
        #pragma unroll
        for (int j = 0; j < 4; ++j) {
            Bt[c4 * 4 + j][kk]      = f2bf(av0[j]);
            Bt[16 + c4 * 4 + j][kk] = f2bf(av1[j]);
        }
        __syncthreads();                       // tile visible
        const unsigned short* zrow = Zw + (size_t)lrow * V + k0 + g * 8;
        #pragma unroll
        for (int ks = 0; ks < 2; ++ks) {
            bf16x8 b0 = *reinterpret_cast<const bf16x8*>(&Bt[lrow][ks * 32 + g * 8]);
            bf16x8 b1 = *reinterpret_cast<const bf16x8*>(&Bt[16 + lrow][ks * 32 + g * 8]);
            bf16x8 a0 = *reinterpret_cast<const bf16x8*>(zrow + ks * 32);
            bf16x8 a1 = *reinterpret_cast<const bf16x8*>(zrow + (size_t)16 * V + ks * 32);
            acc00 = __builtin_amdgcn_mfma_f32_16x16x32_bf16(a0, b0, acc00, 0, 0, 0);
            acc01 = __builtin_amdgcn_mfma_f32_16x16x32_bf16(a0, b1, acc01, 0, 0, 0);
            acc10 = __builtin_amdgcn_mfma_f32_16x16x32_bf16(a1, b0, acc10, 0, 0, 0);
            acc11 = __builtin_amdgcn_mfma_f32_16x16x32_bf16(a1, b1, acc11, 0, 0, 0);
        }
    }

    // C/D layout: col = lane&15, row = (lane>>4)*4 + reg   [verified m89/m91]
    float* Pp = partial + (size_t)(p * 2 + kh) * 128 * V;
    #pragma unroll
    for (int r = 0; r < 4; ++r) {
        const int m0 = wid * 32 + g * 4 + r;
        Pp[(size_t)m0 * V + n0 + lrow]             = acc00[r];
        Pp[(size_t)m0 * V + n0 + 16 + lrow]        = acc01[r];
        Pp[(size_t)(m0 + 16) * V + n0 + lrow]      = acc10[r];
        Pp[(size_t)(m0 + 16) * V + n0 + 16 + lrow] = acc11[r];
    }
}

// ---- kernel 3: out = relu(sum(partials) + sum(fifo[:16] over i,p) + x) -
__global__ __launch_bounds__(256) void k_epi(const float* __restrict__ x,
                                             const float* __restrict__ fifo,
                                             const float* __restrict__ partial,
                                             float* __restrict__ out) {
    const size_t off  = ((size_t)blockIdx.x * 256 + threadIdx.x) * 4;
    const size_t slab = (size_t)128 * V;
    f32x4 s0 = *reinterpret_cast<const f32x4*>(x + off);
    f32x4 s1 = {}, s2 = {}, s3 = {};
    #pragma unroll
    for (int q = 0; q < 6; ++q) {
        f32x4 pv = *reinterpret_cast<const f32x4*>(partial + (size_t)q * slab + off);
        if (q & 1) s1 += pv; else s2 += pv;
    }
    #pragma unroll
    for (int s = 0; s < 48; ++s) {   // fifo[:16] x 3p = first 48 slabs
        f32x4 fv = *reinterpret_cast<const f32x4*>(fifo + (size_t)s * slab + off);
        switch (s & 3) {
            case 0: s0 += fv; break;
            case 1: s1 += fv; break;
            case 2: s2 += fv; break;
            default: s3 += fv; break;
        }
    }
    f32x4 sum = (s0 + s1) + (s2 + s3);
    f32x4 o;
    #pragma unroll
    for (int j = 0; j < 4; ++j) o[j] = fmaxf(sum[j], 0.0f);
    *reinterpret_cast<f32x4*>(out + off) = o;
}

extern "C" void kernel_launch(void* const* d_in, const int* in_sizes, int n_in,
                              void* d_out, int out_size, void* d_ws, size_t ws_size,
                              hipStream_t stream) {
    const float* x    = (const float*)d_in[0];   // (1,128,4096,1)
    const float* A    = (const float*)d_in[1];   // (3,4096,4096)
    const float* fifo = (const float*)d_in[2];   // (17,3,128,4096)
    const float* W    = (const float*)d_in[3];   // (384,128)
    const float* b    = (const float*)d_in[4];   // (384,)
    float* out = (float*)d_out;                  // (1,128,4096) f32

    unsigned short* zb = (unsigned short*)d_ws;                       // 3.0 MB bf16
    float* partial = (float*)((char*)d_ws + (size_t)384 * V * 2);     // 12 MB f32 (6 slabs)

    k_z   <<<dim3(48, 16),   256, 0, stream>>>(x, W, b, zb);
    k_gemm<<<dim3(128, 3, 2), 256, 0, stream>>>(zb, A, partial);
    k_epi <<<dim3(512),       256, 0, stream>>>(x, fifo, partial, out);
}